// Round 2
// baseline (2625.632 us; speedup 1.0000x reference)
//
#include <hip/hip_runtime.h>
#include <hip/hip_bf16.h>

typedef __bf16 bf16;
typedef __bf16 bf16x8 __attribute__((ext_vector_type(8)));
typedef float f32x4 __attribute__((ext_vector_type(4)));

#define NB 4
#define T 8192
#define C 128
#define NBLK 40
#define TILE 32

__device__ __forceinline__ float bf2f(bf16 x){ return (float)x; }
__device__ __forceinline__ bf16 f2bf(float x){ return (bf16)x; }

// Load input element i as float, whatever the harness dtype is (flag: 1=bf16, 0=f32)
__device__ __forceinline__ float ld(const void* p, int i, int isbf){
    return isbf ? bf2f(((const bf16*)p)[i]) : ((const float*)p)[i];
}

// Detect input dtype from x's raw bits. For bf16 data every u16 is a sane
// bf16 (~N(0,1): exponent field 100..140, or zero). For f32 data the even
// u16s are mantissa low-halves -> ~uniform exponent field (~16% "sane").
__global__ __launch_bounds__(64) void k_detect(const unsigned short* __restrict__ u,
                                               int* __restrict__ flag){
    unsigned short v = u[threadIdx.x * 2];
    int e = (v >> 7) & 255;
    bool sane = (e >= 100 && e <= 140) || ((v & 0x7FFF) == 0);
    unsigned long long m = __ballot(sane);
    if (threadIdx.x == 0) *flag = (__popcll(m) >= 48) ? 1 : 0;
}

// Convert ALL inputs into canonical workspace copies:
//   weff [40][256][256] bf16 : weff[blk][o][c]=cw[blk][o][c][0] (tap t-d),
//                              weff[blk][o][128+c]=cw[blk][o][c][1] (tap t)
//   pwc  [40][128][128] bf16, w1c/w2c [128][128] bf16
//   xc [4][8192] f32, cbf [40][256] f32, pbf [40][128] f32
//   misc f32: [0,384) pre_w, [384,512) pre_b, [512,640) lin1_b, [640,768) lin2_b
__global__ __launch_bounds__(256) void k_prep(
    const void* __restrict__ conv_w, const void* __restrict__ post_w,
    const void* __restrict__ lin1_w, const void* __restrict__ lin2_w,
    const void* __restrict__ x,      const void* __restrict__ conv_b,
    const void* __restrict__ post_b, const void* __restrict__ pre_w,
    const void* __restrict__ pre_b,  const void* __restrict__ lin1_b,
    const void* __restrict__ lin2_b,
    bf16* __restrict__ weff, bf16* __restrict__ pwc,
    bf16* __restrict__ w1c,  bf16* __restrict__ w2c,
    float* __restrict__ xc,  float* __restrict__ cbf,
    float* __restrict__ pbf, float* __restrict__ misc,
    const int* __restrict__ flag){
    int f   = *flag;
    int blk = blockIdx.x, tid = threadIdx.x;
    if (blk < 10240){
        int e = blk * 256 + tid;                       // < 2,621,440
        int b_ = e >> 16, o = (e >> 8) & 255, c = (e >> 1) & 127, k = e & 1;
        weff[(b_ << 16) + o * 256 + k * 128 + c] = f2bf(ld(conv_w, e, f));
    } else if (blk < 12800){
        int e = (blk - 10240) * 256 + tid;             // < 655,360
        pwc[e] = f2bf(ld(post_w, e, f));
    } else if (blk < 12864){
        int e = (blk - 12800) * 256 + tid;             // < 16,384
        w1c[e] = f2bf(ld(lin1_w, e, f));
    } else if (blk < 12928){
        int e = (blk - 12864) * 256 + tid;
        w2c[e] = f2bf(ld(lin2_w, e, f));
    } else if (blk < 13056){
        int e = (blk - 12928) * 256 + tid;             // < 32,768
        xc[e] = ld(x, e, f);
    } else if (blk < 13096){
        int e = (blk - 13056) * 256 + tid;             // < 10,240
        cbf[e] = ld(conv_b, e, f);
    } else if (blk < 13116){
        int e = (blk - 13096) * 256 + tid;             // < 5,120
        pbf[e] = ld(post_b, e, f);
    } else {
        int e = (blk - 13116) * 256 + tid;             // < 768
        if      (e < 384) misc[e] = ld(pre_w,  e,       f);
        else if (e < 512) misc[e] = ld(pre_b,  e - 384, f);
        else if (e < 640) misc[e] = ld(lin1_b, e - 512, f);
        else if (e < 768) misc[e] = ld(lin2_b, e - 640, f);
    }
}

// pre_net: h0[b][c][t] = pre_b[c] + sum_k pre_w[c][0][k] * x[b][0][t-2+k]
__global__ __launch_bounds__(256) void k_pre(const float* __restrict__ xc,
                                             const float* __restrict__ misc,
                                             float* __restrict__ h0){
    int e = blockIdx.x * 256 + threadIdx.x;   // e < 4*128*8192
    int t = e & (T - 1);
    int c = (e >> 13) & (C - 1);
    int b = e >> 20;
    float acc = misc[384 + c];
    const float* xr = xc + b * T;
#pragma unroll
    for (int k = 0; k < 3; k++){
        int ts = t - 2 + k;
        float xv = (ts >= 0) ? xr[ts] : 0.f;
        acc += misc[c * 3 + k] * xv;
    }
    h0[(b * C + c) * T + t] = acc;
}

// Fused per-block kernel: conv(GEMM 256x256xN) -> GLU -> post(GEMM 128x128xN)
// One WG = 256 threads (4 waves) owns 32 columns x all 256 rows.
#define XS 264      // Xlds row stride (bf16): 256 + 8 pad
#define SS 136      // Slds row stride (bf16): 128 + 8 pad
#define YS 33       // ylds row stride (f32):  32 + 1 pad
__global__ __launch_bounds__(256) void k_block(const float* __restrict__ hin,
                                               float* __restrict__ hout,
                                               float* __restrict__ ssum,
                                               const bf16*  __restrict__ weff, // [256][256]
                                               const float* __restrict__ cb,   // [256] f32
                                               const bf16*  __restrict__ pw,   // [128][128]
                                               const float* __restrict__ pb,   // [128] f32
                                               int d){
    __shared__ __align__(16) char smem[42496];
    bf16*  Xlds = (bf16*)smem;            // [32][264] phase 0-1
    float* ylds = (float*)smem;           // [256][33] phase 2-3 (aliases Xlds)
    bf16*  Slds = (bf16*)(smem + 33792);  // [32][136]

    int tid = threadIdx.x;
    int wg  = blockIdx.x;                 // 1024 WGs
    int b   = wg >> 8;
    int t0  = (wg & 255) * TILE;

    // ---- phase 0: stage X[ceff][col] transposed into LDS as bf16 ----
    {
        int ceff = tid;                   // 0..255
        int c    = ceff & 127;
        int tap  = ceff >> 7;             // 0 -> t-d, 1 -> t
        const float* src = hin + (b * C + c) * T;
        int toff = t0 - (tap ? 0 : d);
#pragma unroll 8
        for (int col = 0; col < TILE; col++){
            int ts = toff + col;
            float v = (ts >= 0) ? src[ts] : 0.f;
            Xlds[col * XS + ceff] = f2bf(v);
        }
    }
    __syncthreads();

    int wv = tid >> 6, ln = tid & 63;
    int lo = ln & 15, quad = ln >> 4;

    // ---- phase 1: conv GEMM, wave wv owns rows [wv*64, wv*64+64) ----
    f32x4 acc[4][2] = {};
    const bf16* wb = weff + (wv * 64 + lo) * 256 + quad * 8;
#pragma unroll
    for (int kk = 0; kk < 256; kk += 32){
        bf16x8 afr[4], bfr[2];
#pragma unroll
        for (int rt = 0; rt < 4; rt++)
            afr[rt] = *(const bf16x8*)(wb + rt * 16 * 256 + kk);
#pragma unroll
        for (int ct = 0; ct < 2; ct++)
            bfr[ct] = *(const bf16x8*)(Xlds + (ct * 16 + lo) * XS + kk + quad * 8);
#pragma unroll
        for (int rt = 0; rt < 4; rt++)
#pragma unroll
            for (int ct = 0; ct < 2; ct++)
                acc[rt][ct] = __builtin_amdgcn_mfma_f32_16x16x32_bf16(
                    afr[rt], bfr[ct], acc[rt][ct], 0, 0, 0);
    }
    __syncthreads();   // done reading Xlds (ylds aliases it)

    // ---- phase 2: y + bias -> ylds (f32) ----
#pragma unroll
    for (int rt = 0; rt < 4; rt++){
        int rb = wv * 64 + rt * 16 + quad * 4;
#pragma unroll
        for (int ct = 0; ct < 2; ct++){
            int col = ct * 16 + lo;
#pragma unroll
            for (int r = 0; r < 4; r++)
                ylds[(rb + r) * YS + col] = acc[rt][ct][r] + cb[rb + r];
        }
    }
    __syncthreads();

    // ---- phase 3: GLU, skip -> Slds (bf16) + skip_sum RMW (f32) ----
    {
        int j    = tid >> 1;
        int colb = (tid & 1) * 16;
        float* sp = ssum + (b * C + j) * T + t0 + colb;
#pragma unroll
        for (int i = 0; i < 16; i++){
            int col = colb + i;
            float a = ylds[j * YS + col];
            float g = ylds[(j + 128) * YS + col];
            float s = a * (1.f / (1.f + __expf(-g)));
            Slds[col * SS + j] = f2bf(s);
            sp[i] += s;
        }
    }
    __syncthreads();

    // ---- phase 4: post GEMM, wave wv owns rows [wv*32, wv*32+32) ----
    f32x4 pacc[2][2] = {};
#pragma unroll
    for (int kk = 0; kk < 128; kk += 32){
        bf16x8 pa[2], pbv[2];
#pragma unroll
        for (int rt = 0; rt < 2; rt++)
            pa[rt] = *(const bf16x8*)(pw + (wv * 32 + rt * 16 + lo) * 128 + kk + quad * 8);
#pragma unroll
        for (int ct = 0; ct < 2; ct++)
            pbv[ct] = *(const bf16x8*)(Slds + (ct * 16 + lo) * SS + kk + quad * 8);
#pragma unroll
        for (int rt = 0; rt < 2; rt++)
#pragma unroll
            for (int ct = 0; ct < 2; ct++)
                pacc[rt][ct] = __builtin_amdgcn_mfma_f32_16x16x32_bf16(
                    pa[rt], pbv[ct], pacc[rt][ct], 0, 0, 0);
    }

    // ---- phase 5: h_out = h_in + post + post_b ----
#pragma unroll
    for (int rt = 0; rt < 2; rt++){
        int rb = wv * 32 + rt * 16 + quad * 4;
#pragma unroll
        for (int ct = 0; ct < 2; ct++){
            int col = t0 + ct * 16 + lo;
#pragma unroll
            for (int r = 0; r < 4; r++){
                int row = rb + r;
                size_t gi = (size_t)(b * C + row) * T + col;
                hout[gi] = hin[gi] + pacc[rt][ct][r] + pb[row];
            }
        }
    }
}

// Final: relu(skip_sum) -> lin1 -> relu -> lin2 -> out [T][B][C]
__global__ __launch_bounds__(256) void k_final(const float* __restrict__ ssum,
                                               const bf16* __restrict__ w1,
                                               const bf16* __restrict__ w2,
                                               const float* __restrict__ misc,
                                               void* __restrict__ outv,
                                               const int* __restrict__ flag){
    __shared__ __align__(16) bf16 Z[32 * SS];
    __shared__ __align__(16) bf16 U[32 * SS];
    const float* b1 = misc + 512;
    const float* b2 = misc + 640;
    int isbf = *flag;
    int tid = threadIdx.x;
    int wg  = blockIdx.x;
    int b   = wg >> 8;
    int t0  = (wg & 255) * TILE;

    {
        int j    = tid & 127;
        int colb = (tid >> 7) * 16;
        const float* sp = ssum + (b * C + j) * T + t0 + colb;
#pragma unroll
        for (int i = 0; i < 16; i++){
            float z = sp[i];
            Z[(colb + i) * SS + j] = f2bf(z > 0.f ? z : 0.f);
        }
    }
    __syncthreads();

    int wv = tid >> 6, ln = tid & 63;
    int lo = ln & 15, quad = ln >> 4;

    f32x4 a1[2][2] = {};
#pragma unroll
    for (int kk = 0; kk < 128; kk += 32){
        bf16x8 pa[2], pbv[2];
#pragma unroll
        for (int rt = 0; rt < 2; rt++)
            pa[rt] = *(const bf16x8*)(w1 + (wv * 32 + rt * 16 + lo) * 128 + kk + quad * 8);
#pragma unroll
        for (int ct = 0; ct < 2; ct++)
            pbv[ct] = *(const bf16x8*)(Z + (ct * 16 + lo) * SS + kk + quad * 8);
#pragma unroll
        for (int rt = 0; rt < 2; rt++)
#pragma unroll
            for (int ct = 0; ct < 2; ct++)
                a1[rt][ct] = __builtin_amdgcn_mfma_f32_16x16x32_bf16(
                    pa[rt], pbv[ct], a1[rt][ct], 0, 0, 0);
    }
#pragma unroll
    for (int rt = 0; rt < 2; rt++){
        int rb = wv * 32 + rt * 16 + quad * 4;
#pragma unroll
        for (int ct = 0; ct < 2; ct++){
            int col = ct * 16 + lo;
#pragma unroll
            for (int r = 0; r < 4; r++){
                float u = a1[rt][ct][r] + b1[rb + r];
                U[col * SS + (rb + r)] = f2bf(u > 0.f ? u : 0.f);
            }
        }
    }
    __syncthreads();

    f32x4 a2[2][2] = {};
#pragma unroll
    for (int kk = 0; kk < 128; kk += 32){
        bf16x8 pa[2], pbv[2];
#pragma unroll
        for (int rt = 0; rt < 2; rt++)
            pa[rt] = *(const bf16x8*)(w2 + (wv * 32 + rt * 16 + lo) * 128 + kk + quad * 8);
#pragma unroll
        for (int ct = 0; ct < 2; ct++)
            pbv[ct] = *(const bf16x8*)(U + (ct * 16 + lo) * SS + kk + quad * 8);
#pragma unroll
        for (int rt = 0; rt < 2; rt++)
#pragma unroll
            for (int ct = 0; ct < 2; ct++)
                a2[rt][ct] = __builtin_amdgcn_mfma_f32_16x16x32_bf16(
                    pa[rt], pbv[ct], a2[rt][ct], 0, 0, 0);
    }
#pragma unroll
    for (int rt = 0; rt < 2; rt++){
        int rb = wv * 32 + rt * 16 + quad * 4;
#pragma unroll
        for (int ct = 0; ct < 2; ct++){
            int col = t0 + ct * 16 + lo;
#pragma unroll
            for (int r = 0; r < 4; r++){
                int row = rb + r;
                float v = a2[rt][ct][r] + b2[rb + r];
                size_t oi = ((size_t)col * NB + b) * C + row;
                if (isbf) ((bf16*)outv)[oi] = f2bf(v);
                else      ((float*)outv)[oi] = v;
            }
        }
    }
}

extern "C" void kernel_launch(void* const* d_in, const int* in_sizes, int n_in,
                              void* d_out, int out_size, void* d_ws, size_t ws_size,
                              hipStream_t stream){
    const void* x      = d_in[0];
    const void* pre_w  = d_in[1];
    const void* pre_b  = d_in[2];
    const void* conv_w = d_in[3];
    const void* conv_b = d_in[4];
    const void* post_w = d_in[5];
    const void* post_b = d_in[6];
    const void* lin1w  = d_in[7];
    const void* lin1b  = d_in[8];
    const void* lin2w  = d_in[9];
    const void* lin2b  = d_in[10];

    char* ws = (char*)d_ws;
    const size_t HB = (size_t)NB * C * T * 4;          // 16,777,216
    float* h0   = (float*)(ws);
    float* h1   = (float*)(ws + HB);
    float* ssum = (float*)(ws + 2 * HB);
    bf16*  weff = (bf16*) (ws + 3 * HB);               // 5,242,880 B
    bf16*  pwc  = (bf16*) (ws + 3 * HB +  5242880);    // 1,310,720 B
    bf16*  w1c  = (bf16*) (ws + 3 * HB +  6553600);    //    32,768 B
    bf16*  w2c  = (bf16*) (ws + 3 * HB +  6586368);    //    32,768 B
    float* xc   = (float*)(ws + 3 * HB +  6619136);    //   131,072 B
    float* cbf  = (float*)(ws + 3 * HB +  6750208);    //    40,960 B
    float* pbf  = (float*)(ws + 3 * HB +  6791168);    //    20,480 B
    float* misc = (float*)(ws + 3 * HB +  6811648);    //     3,072 B
    int*   flag = (int*)  (ws + 3 * HB +  6814720);    // total ~54.5 MiB

    hipMemsetAsync(ssum, 0, HB, stream);
    k_detect<<<1, 64, 0, stream>>>((const unsigned short*)x, flag);
    k_prep<<<13119, 256, 0, stream>>>(conv_w, post_w, lin1w, lin2w, x, conv_b,
                                      post_b, pre_w, pre_b, lin1b, lin2b,
                                      weff, pwc, w1c, w2c, xc, cbf, pbf, misc, flag);
    k_pre<<<16384, 256, 0, stream>>>(xc, misc, h0);

    for (int i = 0; i < NBLK; i++){
        int d = 1 << (i % 10);
        const float* hin = (i & 1) ? h1 : h0;
        float*       hout= (i & 1) ? h0 : h1;
        k_block<<<1024, 256, 0, stream>>>(hin, hout, ssum,
            weff + (size_t)i * 65536, cbf + i * 256,
            pwc + (size_t)i * 16384, pbf + i * 128, d);
    }
    k_final<<<1024, 256, 0, stream>>>(ssum, w1c, w2c, misc, d_out, flag);
}

// Round 3
// 2320.540 us; speedup vs baseline: 1.1315x; 1.1315x over previous
//
#include <hip/hip_runtime.h>
#include <hip/hip_bf16.h>
#include <hip/hip_cooperative_groups.h>

namespace cg = cooperative_groups;

typedef __bf16 bf16;
typedef __bf16 bf16x8 __attribute__((ext_vector_type(8)));
typedef __bf16 bf16x4 __attribute__((ext_vector_type(4)));
typedef float f32x4 __attribute__((ext_vector_type(4)));

#define NB 4
#define T 8192
#define C 128
#define NBLK 40
#define SS 136   // Slds row stride (bf16): 128 + 8

__device__ __forceinline__ float bf2f(bf16 x){ return (float)x; }
__device__ __forceinline__ bf16 f2bf(float x){ return (bf16)x; }

// Load input element i as float, whatever the harness dtype is (flag: 1=bf16, 0=f32)
__device__ __forceinline__ float ld(const void* p, int i, int isbf){
    return isbf ? bf2f(((const bf16*)p)[i]) : ((const float*)p)[i];
}

// Detect input dtype from x's raw bits (see R1 notes): bf16 -> ~all low-u16s
// have sane exponents; f32 -> low halves are mantissa noise.
__global__ __launch_bounds__(64) void k_detect(const unsigned short* __restrict__ u,
                                               int* __restrict__ flag){
    unsigned short v = u[threadIdx.x * 2];
    int e = (v >> 7) & 255;
    bool sane = (e >= 100 && e <= 140) || ((v & 0x7FFF) == 0);
    unsigned long long m = __ballot(sane);
    if (threadIdx.x == 0) *flag = (__popcll(m) >= 48) ? 1 : 0;
}

// Canonicalize all inputs into workspace (bf16 weights, f32 x/biases).
//   weff [40][256][256] bf16 : weff[blk][o][c]=cw[blk][o][c][0] (tap t-d),
//                              weff[blk][o][128+c]=cw[blk][o][c][1] (tap t)
//   misc f32: [0,384) pre_w, [384,512) pre_b, [512,640) lin1_b, [640,768) lin2_b
__global__ __launch_bounds__(256) void k_prep(
    const void* __restrict__ conv_w, const void* __restrict__ post_w,
    const void* __restrict__ lin1_w, const void* __restrict__ lin2_w,
    const void* __restrict__ x,      const void* __restrict__ conv_b,
    const void* __restrict__ post_b, const void* __restrict__ pre_w,
    const void* __restrict__ pre_b,  const void* __restrict__ lin1_b,
    const void* __restrict__ lin2_b,
    bf16* __restrict__ weff, bf16* __restrict__ pwc,
    bf16* __restrict__ w1c,  bf16* __restrict__ w2c,
    float* __restrict__ xc,  float* __restrict__ cbf,
    float* __restrict__ pbf, float* __restrict__ misc,
    const int* __restrict__ flag){
    int f   = *flag;
    int blk = blockIdx.x, tid = threadIdx.x;
    if (blk < 10240){
        int e = blk * 256 + tid;                       // < 2,621,440
        int b_ = e >> 16, o = (e >> 8) & 255, c = (e >> 1) & 127, k = e & 1;
        weff[(b_ << 16) + o * 256 + k * 128 + c] = f2bf(ld(conv_w, e, f));
    } else if (blk < 12800){
        int e = (blk - 10240) * 256 + tid;             // < 655,360
        pwc[e] = f2bf(ld(post_w, e, f));
    } else if (blk < 12864){
        int e = (blk - 12800) * 256 + tid;             // < 16,384
        w1c[e] = f2bf(ld(lin1_w, e, f));
    } else if (blk < 12928){
        int e = (blk - 12864) * 256 + tid;
        w2c[e] = f2bf(ld(lin2_w, e, f));
    } else if (blk < 13056){
        int e = (blk - 12928) * 256 + tid;             // < 32,768
        xc[e] = ld(x, e, f);
    } else if (blk < 13096){
        int e = (blk - 13056) * 256 + tid;             // < 10,240
        cbf[e] = ld(conv_b, e, f);
    } else if (blk < 13116){
        int e = (blk - 13096) * 256 + tid;             // < 5,120
        pbf[e] = ld(post_b, e, f);
    } else {
        int e = (blk - 13116) * 256 + tid;             // < 768
        if      (e < 384) misc[e] = ld(pre_w,  e,       f);
        else if (e < 512) misc[e] = ld(pre_b,  e - 384, f);
        else if (e < 640) misc[e] = ld(lin1_b, e - 512, f);
        else if (e < 768) misc[e] = ld(lin2_b, e - 640, f);
    }
}

// Persistent cooperative kernel: pre-net + 40 fused blocks + final MLP.
// 256 WGs x 512 threads (8 waves); WG owns batch b = wg>>6, cols [t0, t0+128).
// Wave wv owns conv a-rows [wv*16,+16) and g-rows [128+wv*16,+16) -> GLU in
// registers. h residual stream: exact f32 in registers (own tile only);
// bf16 shadow in global ([b][t][c], c contiguous) for cross-WG dilated taps.
// skip_sum: f32 registers across all 40 blocks.
__global__ __launch_bounds__(512, 2) void k_main(
    const float* __restrict__ xc,  const float* __restrict__ misc,
    const bf16* __restrict__ weff, const float* __restrict__ cbf,
    const bf16* __restrict__ pwc,  const float* __restrict__ pbf,
    const bf16* __restrict__ w1c,  const bf16* __restrict__ w2c,
    bf16* __restrict__ hA, bf16* __restrict__ hB,
    void* __restrict__ outv, const int* __restrict__ flag)
{
    cg::grid_group grid = cg::this_grid();
    __shared__ __align__(16) bf16 Slds[128 * SS];   // 34,816 B

    int tid = threadIdx.x;
    int wg  = blockIdx.x;              // 256 WGs
    int b   = wg >> 6;
    int t0  = (wg & 63) * 128;
    int wv  = tid >> 6, ln = tid & 63, lo = ln & 15, quad = ln >> 4;
    const size_t hb = (size_t)b * T * C;

    float hreg[32];   // h[c = wv*16+quad*4+r][t = t0+ct*16+lo], idx ct*4+r
    float ssum[32];   // skip_sum, same coords (j = wv*16+quad*4+r)

    // ---- pre-net: fill hreg + bf16 shadow ----
    {
        const float* xr = xc + b * T;
#pragma unroll
        for (int ct = 0; ct < 8; ct++){
            int t = t0 + ct * 16 + lo;
            float x0 = (t >= 2) ? xr[t - 2] : 0.f;
            float x1 = (t >= 1) ? xr[t - 1] : 0.f;
            float x2 = xr[t];
            bf16x4 hv;
#pragma unroll
            for (int r = 0; r < 4; r++){
                int c = wv * 16 + quad * 4 + r;
                float acc = misc[384 + c] + misc[c*3]*x0 + misc[c*3+1]*x1 + misc[c*3+2]*x2;
                hreg[ct * 4 + r] = acc;
                hv[r] = f2bf(acc);
            }
            *(bf16x4*)(hA + hb + (size_t)t * C + wv * 16 + quad * 4) = hv;
        }
    }
#pragma unroll
    for (int i = 0; i < 32; i++) ssum[i] = 0.f;
    grid.sync();

    // ---- 40 residual blocks ----
    for (int blk = 0; blk < NBLK; blk++){
        int d = 1 << (blk % 10);
        const bf16* hin  = (blk & 1) ? hB : hA;
        bf16*       hout = (blk & 1) ? hA : hB;
        const bf16* wb   = weff + ((size_t)blk << 16);
        const bf16* pwb  = pwc  + blk * 16384;
        const float* cb  = cbf + blk * 256;
        const float* pb  = pbf + blk * 128;

        // conv GEMM: rows (a: wv*16.., g: 128+wv*16..) x K=256 x 128 cols
        f32x4 cacc[2][8] = {};
#pragma unroll
        for (int kk = 0; kk < 8; kk++){
            int coff = (kk & 3) * 32;
            int dd   = (kk < 4) ? d : 0;     // K 0..127 = tap t-d, 128..255 = tap t
            bf16x8 afr0 = *(const bf16x8*)(wb + (size_t)(wv*16 + lo) * 256 + kk*32 + quad*8);
            bf16x8 afr1 = *(const bf16x8*)(wb + (size_t)(128 + wv*16 + lo) * 256 + kk*32 + quad*8);
            bf16x8 bfr[8];
            bf16x8 zz = {};
#pragma unroll
            for (int ct = 0; ct < 8; ct++){
                int t  = t0 + ct * 16 + lo - dd;
                int tc = (t < 0) ? 0 : t;
                bf16x8 v = *(const bf16x8*)(hin + hb + (size_t)tc * C + coff + quad * 8);
                bfr[ct] = (t < 0) ? zz : v;
            }
#pragma unroll
            for (int ct = 0; ct < 8; ct++){
                cacc[0][ct] = __builtin_amdgcn_mfma_f32_16x16x32_bf16(afr0, bfr[ct], cacc[0][ct], 0, 0, 0);
                cacc[1][ct] = __builtin_amdgcn_mfma_f32_16x16x32_bf16(afr1, bfr[ct], cacc[1][ct], 0, 0, 0);
            }
        }

        // GLU in registers -> ssum regs + Slds (bf16, B-operand-ready)
#pragma unroll
        for (int ct = 0; ct < 8; ct++){
            int col = ct * 16 + lo;
            bf16x4 sv;
#pragma unroll
            for (int r = 0; r < 4; r++){
                int j = wv * 16 + quad * 4 + r;
                float a = cacc[0][ct][r] + cb[j];
                float g = cacc[1][ct][r] + cb[128 + j];
                float s = a * (1.f / (1.f + __expf(-g)));
                ssum[ct * 4 + r] += s;
                sv[r] = f2bf(s);
            }
            *(bf16x4*)(Slds + col * SS + wv * 16 + quad * 4) = sv;
        }
        __syncthreads();

        // post GEMM (128x128xK128) + residual in registers + bf16 shadow write
        f32x4 pacc[8] = {};
#pragma unroll
        for (int kk = 0; kk < 4; kk++){
            bf16x8 pa = *(const bf16x8*)(pwb + (wv*16 + lo) * 128 + kk*32 + quad*8);
#pragma unroll
            for (int ct = 0; ct < 8; ct++){
                bf16x8 pbv = *(const bf16x8*)(Slds + (ct*16 + lo) * SS + kk*32 + quad*8);
                pacc[ct] = __builtin_amdgcn_mfma_f32_16x16x32_bf16(pa, pbv, pacc[ct], 0, 0, 0);
            }
        }
#pragma unroll
        for (int ct = 0; ct < 8; ct++){
            int t = t0 + ct * 16 + lo;
            bf16x4 hv;
#pragma unroll
            for (int r = 0; r < 4; r++){
                int row = wv * 16 + quad * 4 + r;
                float hn = hreg[ct * 4 + r] + pacc[ct][r] + pb[row];
                hreg[ct * 4 + r] = hn;
                hv[r] = f2bf(hn);
            }
            *(bf16x4*)(hout + hb + (size_t)t * C + wv * 16 + quad * 4) = hv;
        }
        grid.sync();
    }

    // ---- final: relu(ssum) -> lin1 -> relu -> lin2 -> out [T][B][C] ----
    const float* b1 = misc + 512;
    const float* b2 = misc + 640;
#pragma unroll
    for (int ct = 0; ct < 8; ct++){
        int col = ct * 16 + lo;
        bf16x4 zv;
#pragma unroll
        for (int r = 0; r < 4; r++){
            float z = ssum[ct * 4 + r];
            zv[r] = f2bf(z > 0.f ? z : 0.f);
        }
        *(bf16x4*)(Slds + col * SS + wv * 16 + quad * 4) = zv;
    }
    __syncthreads();

    f32x4 a1[8] = {};
#pragma unroll
    for (int kk = 0; kk < 4; kk++){
        bf16x8 pa = *(const bf16x8*)(w1c + (wv*16 + lo) * 128 + kk*32 + quad*8);
#pragma unroll
        for (int ct = 0; ct < 8; ct++){
            bf16x8 pbv = *(const bf16x8*)(Slds + (ct*16 + lo) * SS + kk*32 + quad*8);
            a1[ct] = __builtin_amdgcn_mfma_f32_16x16x32_bf16(pa, pbv, a1[ct], 0, 0, 0);
        }
    }
    __syncthreads();   // all Z reads done before overwriting Slds with U
#pragma unroll
    for (int ct = 0; ct < 8; ct++){
        int col = ct * 16 + lo;
        bf16x4 uv;
#pragma unroll
        for (int r = 0; r < 4; r++){
            int row = wv * 16 + quad * 4 + r;
            float u = a1[ct][r] + b1[row];
            uv[r] = f2bf(u > 0.f ? u : 0.f);
        }
        *(bf16x4*)(Slds + col * SS + wv * 16 + quad * 4) = uv;
    }
    __syncthreads();

    f32x4 a2[8] = {};
#pragma unroll
    for (int kk = 0; kk < 4; kk++){
        bf16x8 pa = *(const bf16x8*)(w2c + (wv*16 + lo) * 128 + kk*32 + quad*8);
#pragma unroll
        for (int ct = 0; ct < 8; ct++){
            bf16x8 pbv = *(const bf16x8*)(Slds + (ct*16 + lo) * SS + kk*32 + quad*8);
            a2[ct] = __builtin_amdgcn_mfma_f32_16x16x32_bf16(pa, pbv, a2[ct], 0, 0, 0);
        }
    }
    int isbf = *flag;
#pragma unroll
    for (int ct = 0; ct < 8; ct++){
        int col = t0 + ct * 16 + lo;
#pragma unroll
        for (int r = 0; r < 4; r++){
            int row = wv * 16 + quad * 4 + r;
            float v = a2[ct][r] + b2[row];
            size_t oi = ((size_t)col * NB + b) * C + row;
            if (isbf) ((bf16*)outv)[oi] = f2bf(v);
            else      ((float*)outv)[oi] = v;
        }
    }
}

extern "C" void kernel_launch(void* const* d_in, const int* in_sizes, int n_in,
                              void* d_out, int out_size, void* d_ws, size_t ws_size,
                              hipStream_t stream){
    const void* x      = d_in[0];
    const void* pre_w  = d_in[1];
    const void* pre_b  = d_in[2];
    const void* conv_w = d_in[3];
    const void* conv_b = d_in[4];
    const void* post_w = d_in[5];
    const void* post_b = d_in[6];
    const void* lin1w  = d_in[7];
    const void* lin1b  = d_in[8];
    const void* lin2w  = d_in[9];
    const void* lin2b  = d_in[10];

    char* ws = (char*)d_ws;
    bf16*  hA   = (bf16*) (ws);                        //  8,388,608 B
    bf16*  hB   = (bf16*) (ws +  8388608);             //  8,388,608 B
    bf16*  weff = (bf16*) (ws + 16777216);             //  5,242,880 B
    bf16*  pwc  = (bf16*) (ws + 22020096);             //  1,310,720 B
    bf16*  w1c  = (bf16*) (ws + 23330816);             //     32,768 B
    bf16*  w2c  = (bf16*) (ws + 23363584);             //     32,768 B
    float* xc   = (float*)(ws + 23396352);             //    131,072 B
    float* cbf  = (float*)(ws + 23527424);             //     40,960 B
    float* pbf  = (float*)(ws + 23568384);             //     20,480 B
    float* misc = (float*)(ws + 23588864);             //      3,072 B
    int*   flag = (int*)  (ws + 23591936);             // total ~23.6 MiB

    k_detect<<<1, 64, 0, stream>>>((const unsigned short*)x, flag);
    k_prep<<<13119, 256, 0, stream>>>(conv_w, post_w, lin1w, lin2w, x, conv_b,
                                      post_b, pre_w, pre_b, lin1b, lin2b,
                                      weff, pwc, w1c, w2c, xc, cbf, pbf, misc, flag);

    const float* xc_c   = xc;   const float* misc_c = misc;
    const bf16*  weff_c = weff; const float* cbf_c  = cbf;
    const bf16*  pwc_c  = pwc;  const float* pbf_c  = pbf;
    const bf16*  w1c_c  = w1c;  const bf16*  w2c_c  = w2c;
    void* out_v = d_out;        const int* flag_c = flag;
    void* ka[12] = { &xc_c, &misc_c, &weff_c, &cbf_c, &pwc_c, &pbf_c,
                     &w1c_c, &w2c_c, &hA, &hB, &out_v, &flag_c };
    hipLaunchCooperativeKernel((void*)k_main, dim3(256), dim3(512), ka, 0, stream);
}

// Round 4
// 1466.378 us; speedup vs baseline: 1.7906x; 1.5825x over previous
//
#include <hip/hip_runtime.h>
#include <hip/hip_bf16.h>

typedef __bf16 bf16;
typedef __bf16 bf16x8 __attribute__((ext_vector_type(8)));
typedef __bf16 bf16x4 __attribute__((ext_vector_type(4)));
typedef float f32x4 __attribute__((ext_vector_type(4)));

#define NB 4
#define T 8192
#define C 128
#define NBLK 40
#define XS 136   // X row stride (bf16): 128 ch + 8 pad  (272B, 16B-aligned rows, bank-balanced)
#define SS 136   // S row stride (bf16)

#define MFMA(a, b, c) __builtin_amdgcn_mfma_f32_16x16x32_bf16(a, b, c, 0, 0, 0)

__device__ __forceinline__ float bf2f(bf16 x){ return (float)x; }
__device__ __forceinline__ bf16 f2bf(float x){ return (bf16)x; }

__device__ __forceinline__ float ld(const void* p, int i, int isbf){
    return isbf ? bf2f(((const bf16*)p)[i]) : ((const float*)p)[i];
}

// Detect input dtype from x's raw bits (bf16 -> low u16s have sane exponents).
__global__ __launch_bounds__(64) void k_detect(const unsigned short* __restrict__ u,
                                               int* __restrict__ flag){
    unsigned short v = u[threadIdx.x * 2];
    int e = (v >> 7) & 255;
    bool sane = (e >= 100 && e <= 140) || ((v & 0x7FFF) == 0);
    unsigned long long m = __ballot(sane);
    if (threadIdx.x == 0) *flag = (__popcll(m) >= 48) ? 1 : 0;
}

// Canonicalize inputs: weff [40][256][256] bf16 (K = [tap t-d ch0..127 | tap t ch0..127]),
// pwc [40][128][128] bf16, w1c/w2c bf16, xc f32, cbf/pbf f32,
// misc f32: [0,384) pre_w, [384,512) pre_b, [512,640) lin1_b, [640,768) lin2_b
__global__ __launch_bounds__(256) void k_prep(
    const void* __restrict__ conv_w, const void* __restrict__ post_w,
    const void* __restrict__ lin1_w, const void* __restrict__ lin2_w,
    const void* __restrict__ x,      const void* __restrict__ conv_b,
    const void* __restrict__ post_b, const void* __restrict__ pre_w,
    const void* __restrict__ pre_b,  const void* __restrict__ lin1_b,
    const void* __restrict__ lin2_b,
    bf16* __restrict__ weff, bf16* __restrict__ pwc,
    bf16* __restrict__ w1c,  bf16* __restrict__ w2c,
    float* __restrict__ xc,  float* __restrict__ cbf,
    float* __restrict__ pbf, float* __restrict__ misc,
    const int* __restrict__ flag){
    int f   = *flag;
    int blk = blockIdx.x, tid = threadIdx.x;
    if (blk < 10240){
        int e = blk * 256 + tid;
        int b_ = e >> 16, o = (e >> 8) & 255, c = (e >> 1) & 127, k = e & 1;
        weff[(b_ << 16) + o * 256 + k * 128 + c] = f2bf(ld(conv_w, e, f));
    } else if (blk < 12800){
        int e = (blk - 10240) * 256 + tid;
        pwc[e] = f2bf(ld(post_w, e, f));
    } else if (blk < 12864){
        int e = (blk - 12800) * 256 + tid;
        w1c[e] = f2bf(ld(lin1_w, e, f));
    } else if (blk < 12928){
        int e = (blk - 12864) * 256 + tid;
        w2c[e] = f2bf(ld(lin2_w, e, f));
    } else if (blk < 13056){
        int e = (blk - 12928) * 256 + tid;
        xc[e] = ld(x, e, f);
    } else if (blk < 13096){
        int e = (blk - 13056) * 256 + tid;
        cbf[e] = ld(conv_b, e, f);
    } else if (blk < 13116){
        int e = (blk - 13096) * 256 + tid;
        pbf[e] = ld(post_b, e, f);
    } else {
        int e = (blk - 13116) * 256 + tid;
        if      (e < 384) misc[e] = ld(pre_w,  e,       f);
        else if (e < 512) misc[e] = ld(pre_b,  e - 384, f);
        else if (e < 640) misc[e] = ld(lin1_b, e - 512, f);
        else if (e < 768) misc[e] = ld(lin2_b, e - 640, f);
    }
}

__device__ __forceinline__ void wait_ge(unsigned* p, unsigned v){
    int guard = 0;
    while (__hip_atomic_load(p, __ATOMIC_RELAXED, __HIP_MEMORY_SCOPE_AGENT) < v){
        __builtin_amdgcn_s_sleep(1);
        if (++guard > (1 << 28)) break;   // failsafe against protocol bugs
    }
}

// Persistent kernel, 256 WGs x 512 threads, 1 WG/CU. WG = (batch b, slab of 128 cols).
// Dataflow sync: prog[w] = stages published (pre-net=1, layer i => i+2);
//                cons[w] = stages consumed (layer i read => i+1).
// Layer i: left dep = prog[w-D] >= i+1, D = max(1, d/128) (single slab: d%128==0 for d>=128).
// WAR (2-buffer reuse): writer of stage i+1 needs cons[w+Dprev] >= i.
__global__ __launch_bounds__(512, 2) void k_main(
    const float* __restrict__ xc,  const float* __restrict__ misc,
    const bf16* __restrict__ weff, const float* __restrict__ cbf,
    const bf16* __restrict__ pwc,  const float* __restrict__ pbf,
    const bf16* __restrict__ w1c,  const bf16* __restrict__ w2c,
    bf16* __restrict__ hA, bf16* __restrict__ hB,
    unsigned* __restrict__ prog, unsigned* __restrict__ cons,
    void* __restrict__ outv, const int* __restrict__ flag)
{
    __shared__ __align__(16) bf16 X[64 * XS];   // 17408 B, one 64-row tap tile
    __shared__ __align__(16) bf16 S[64 * SS];   // 17408 B, skip / Z / U tiles

    int tid  = threadIdx.x;
    int wg   = blockIdx.x;             // 256
    int b    = wg >> 6;
    int slab = wg & 63;
    int t0   = slab * 128;
    int wv = tid >> 6, ln = tid & 63, lo = ln & 15, quad = ln >> 4;
    const size_t hb = (size_t)b * T * C;

    float hreg[32];   // h[c = wv*16+quad*4+r][t = t0+ct*16+lo], idx ct*4+r (ct global 0..7)
    float ssum[32];

    // ---- pre-net ----
    {
        const float* xr = xc + b * T;
#pragma unroll
        for (int ct = 0; ct < 8; ct++){
            int t = t0 + ct * 16 + lo;
            float x0 = (t >= 2) ? xr[t - 2] : 0.f;
            float x1 = (t >= 1) ? xr[t - 1] : 0.f;
            float x2 = xr[t];
            bf16x4 hv;
#pragma unroll
            for (int r = 0; r < 4; r++){
                int c = wv * 16 + quad * 4 + r;
                float acc = misc[384 + c] + misc[c*3]*x0 + misc[c*3+1]*x1 + misc[c*3+2]*x2;
                hreg[ct * 4 + r] = acc;
                hv[r] = f2bf(acc);
            }
            *(bf16x4*)(hA + hb + (size_t)t * C + wv * 16 + quad * 4) = hv;
        }
    }
#pragma unroll
    for (int i = 0; i < 32; i++) ssum[i] = 0.f;
    __syncthreads();
    if (tid == 0){
        __threadfence();                                    // release h writes
        __hip_atomic_store(prog + wg, 1u, __ATOMIC_RELAXED, __HIP_MEMORY_SCOPE_AGENT);
    }

    // ---- 40 residual blocks ----
    for (int i = 0; i < NBLK; i++){
        int d = 1 << (i % 10);
        int D = (d >= 128) ? (d >> 7) : 1;
        const bf16* hin  = (i & 1) ? hB : hA;
        bf16*       hout = (i & 1) ? hA : hB;
        const bf16* wb   = weff + ((size_t)i << 16);
        const bf16* pwb  = pwc  + i * 16384;
        const float* cb  = cbf + i * 256;
        const float* pb  = pbf + i * 128;

        if (tid == 0){
            if (slab >= D) wait_ge(prog + (wg - D), (unsigned)(i + 1));
            if (i >= 1){
                int dp = 1 << ((i - 1) % 10);
                int Dp = (dp >= 128) ? (dp >> 7) : 1;
                if (slab + Dp <= 63) wait_ge(cons + (wg + Dp), (unsigned)i);
            }
            __threadfence();                                // acquire: inv stale L1/L2
        }
        __syncthreads();

        for (int H = 0; H < 2; H++){
            f32x4 cacc[2][4] = {};
#pragma unroll
            for (int tap = 0; tap < 2; tap++){
                int tbase = t0 + H * 64 - (tap ? 0 : d);
                // stage 64 rows x 128 ch of hin (coalesced, dedup across waves)
#pragma unroll
                for (int j = 0; j < 2; j++){
                    int chunk = j * 512 + tid;              // 1024 granules of 16B
                    int row = chunk >> 4, cs = chunk & 15;
                    int t = tbase + row;
                    bf16x8 v = {};
                    if (t >= 0) v = *(const bf16x8*)(hin + hb + (size_t)t * C + cs * 8);
                    *(bf16x8*)(X + row * XS + cs * 8) = v;
                }
                __syncthreads();
                if (H == 1 && tap == 0 && tid == 0)         // all stage-i neighbor reads done
                    __hip_atomic_store(cons + wg, (unsigned)(i + 1),
                                       __ATOMIC_RELAXED, __HIP_MEMORY_SCOPE_AGENT);
                // conv quarter-K: weff K = tap*128 + kk4*32 + quad*8
#pragma unroll
                for (int kk4 = 0; kk4 < 4; kk4++){
                    int ko = tap * 128 + kk4 * 32 + quad * 8;
                    bf16x8 afr0 = *(const bf16x8*)(wb + (size_t)(wv*16 + lo) * 256 + ko);
                    bf16x8 afr1 = *(const bf16x8*)(wb + (size_t)(128 + wv*16 + lo) * 256 + ko);
#pragma unroll
                    for (int ct = 0; ct < 4; ct++){
                        bf16x8 bfr = *(const bf16x8*)(X + (ct*16 + lo) * XS + kk4*32 + quad*8);
                        cacc[0][ct] = MFMA(afr0, bfr, cacc[0][ct]);
                        cacc[1][ct] = MFMA(afr1, bfr, cacc[1][ct]);
                    }
                }
                __syncthreads();   // X reads done before restage
            }

            // GLU -> ssum regs + S (bf16, post-B-operand layout)
#pragma unroll
            for (int ct = 0; ct < 4; ct++){
                int col = ct * 16 + lo;
                bf16x4 sv;
#pragma unroll
                for (int r = 0; r < 4; r++){
                    int j = wv * 16 + quad * 4 + r;
                    float a = cacc[0][ct][r] + cb[j];
                    float g = cacc[1][ct][r] + cb[128 + j];
                    float s = a * (1.f / (1.f + __expf(-g)));
                    ssum[(H * 4 + ct) * 4 + r] += s;
                    sv[r] = f2bf(s);
                }
                *(bf16x4*)(S + col * SS + wv * 16 + quad * 4) = sv;
            }
            __syncthreads();

            // post GEMM (128 rows x K=128 x 64 cols) + residual + shadow write
            f32x4 pacc[4] = {};
#pragma unroll
            for (int kk = 0; kk < 4; kk++){
                bf16x8 pa = *(const bf16x8*)(pwb + (wv*16 + lo) * 128 + kk*32 + quad*8);
#pragma unroll
                for (int ct = 0; ct < 4; ct++){
                    bf16x8 pbv = *(const bf16x8*)(S + (ct*16 + lo) * SS + kk*32 + quad*8);
                    pacc[ct] = MFMA(pa, pbv, pacc[ct]);
                }
            }
#pragma unroll
            for (int ct = 0; ct < 4; ct++){
                int t = t0 + H * 64 + ct * 16 + lo;
                bf16x4 hv;
#pragma unroll
                for (int r = 0; r < 4; r++){
                    int row = wv * 16 + quad * 4 + r;
                    float hn = hreg[(H * 4 + ct) * 4 + r] + pacc[ct][r] + pb[row];
                    hreg[(H * 4 + ct) * 4 + r] = hn;
                    hv[r] = f2bf(hn);
                }
                *(bf16x4*)(hout + hb + (size_t)t * C + wv * 16 + quad * 4) = hv;
            }
            __syncthreads();   // S reads done; stores drained
        }

        if (tid == 0){
            __threadfence();                                // release hout
            __hip_atomic_store(prog + wg, (unsigned)(i + 2),
                               __ATOMIC_RELAXED, __HIP_MEMORY_SCOPE_AGENT);
        }
    }

    // ---- final: relu(ssum) -> lin1 -> relu -> lin2 -> out [T][B][C] ----
    const float* b1 = misc + 512;
    const float* b2 = misc + 640;
    int isbf = *flag;
    for (int H = 0; H < 2; H++){
#pragma unroll
        for (int ct = 0; ct < 4; ct++){
            int col = ct * 16 + lo;
            bf16x4 zv;
#pragma unroll
            for (int r = 0; r < 4; r++){
                float z = ssum[(H * 4 + ct) * 4 + r];
                zv[r] = f2bf(z > 0.f ? z : 0.f);
            }
            *(bf16x4*)(S + col * SS + wv * 16 + quad * 4) = zv;
        }
        __syncthreads();
        f32x4 a1[4] = {};
#pragma unroll
        for (int kk = 0; kk < 4; kk++){
            bf16x8 pa = *(const bf16x8*)(w1c + (wv*16 + lo) * 128 + kk*32 + quad*8);
#pragma unroll
            for (int ct = 0; ct < 4; ct++){
                bf16x8 pbv = *(const bf16x8*)(S + (ct*16 + lo) * SS + kk*32 + quad*8);
                a1[ct] = MFMA(pa, pbv, a1[ct]);
            }
        }
        __syncthreads();
#pragma unroll
        for (int ct = 0; ct < 4; ct++){
            int col = ct * 16 + lo;
            bf16x4 uv;
#pragma unroll
            for (int r = 0; r < 4; r++){
                int row = wv * 16 + quad * 4 + r;
                float u = a1[ct][r] + b1[row];
                uv[r] = f2bf(u > 0.f ? u : 0.f);
            }
            *(bf16x4*)(S + col * SS + wv * 16 + quad * 4) = uv;
        }
        __syncthreads();
        f32x4 a2[4] = {};
#pragma unroll
        for (int kk = 0; kk < 4; kk++){
            bf16x8 pa = *(const bf16x8*)(w2c + (wv*16 + lo) * 128 + kk*32 + quad*8);
#pragma unroll
            for (int ct = 0; ct < 4; ct++){
                bf16x8 pbv = *(const bf16x8*)(S + (ct*16 + lo) * SS + kk*32 + quad*8);
                a2[ct] = MFMA(pa, pbv, a2[ct]);
            }
        }
#pragma unroll
        for (int ct = 0; ct < 4; ct++){
            int col = t0 + H * 64 + ct * 16 + lo;
#pragma unroll
            for (int r = 0; r < 4; r++){
                int row = wv * 16 + quad * 4 + r;
                float v = a2[ct][r] + b2[row];
                size_t oi = ((size_t)col * NB + b) * C + row;
                if (isbf) ((bf16*)outv)[oi] = f2bf(v);
                else      ((float*)outv)[oi] = v;
            }
        }
        __syncthreads();   // U reads done before next half reuses S
    }
}

extern "C" void kernel_launch(void* const* d_in, const int* in_sizes, int n_in,
                              void* d_out, int out_size, void* d_ws, size_t ws_size,
                              hipStream_t stream){
    const void* x      = d_in[0];
    const void* pre_w  = d_in[1];
    const void* pre_b  = d_in[2];
    const void* conv_w = d_in[3];
    const void* conv_b = d_in[4];
    const void* post_w = d_in[5];
    const void* post_b = d_in[6];
    const void* lin1w  = d_in[7];
    const void* lin1b  = d_in[8];
    const void* lin2w  = d_in[9];
    const void* lin2b  = d_in[10];

    char* ws = (char*)d_ws;
    bf16*     hA   = (bf16*)    (ws);                   //  8,388,608 B
    bf16*     hB   = (bf16*)    (ws +  8388608);        //  8,388,608 B
    bf16*     weff = (bf16*)    (ws + 16777216);        //  5,242,880 B
    bf16*     pwc  = (bf16*)    (ws + 22020096);        //  1,310,720 B
    bf16*     w1c  = (bf16*)    (ws + 23330816);        //     32,768 B
    bf16*     w2c  = (bf16*)    (ws + 23363584);        //     32,768 B
    float*    xc   = (float*)   (ws + 23396352);        //    131,072 B
    float*    cbf  = (float*)   (ws + 23527424);        //     40,960 B
    float*    pbf  = (float*)   (ws + 23568384);        //     20,480 B
    float*    misc = (float*)   (ws + 23588864);        //      3,072 B
    int*      flag = (int*)     (ws + 23591936);        //          4 B
    unsigned* prog = (unsigned*)(ws + 23592960);        //      1,024 B
    unsigned* cons = (unsigned*)(ws + 23593984);        //      1,024 B

    hipMemsetAsync(prog, 0, 2048, stream);
    k_detect<<<1, 64, 0, stream>>>((const unsigned short*)x, flag);
    k_prep<<<13119, 256, 0, stream>>>(conv_w, post_w, lin1w, lin2w, x, conv_b,
                                      post_b, pre_w, pre_b, lin1b, lin2b,
                                      weff, pwc, w1c, w2c, xc, cbf, pbf, misc, flag);

    const float* xc_c   = xc;   const float* misc_c = misc;
    const bf16*  weff_c = weff; const float* cbf_c  = cbf;
    const bf16*  pwc_c  = pwc;  const float* pbf_c  = pbf;
    const bf16*  w1c_c  = w1c;  const bf16*  w2c_c  = w2c;
    void* out_v = d_out;        const int* flag_c = flag;
    void* ka[14] = { &xc_c, &misc_c, &weff_c, &cbf_c, &pwc_c, &pbf_c,
                     &w1c_c, &w2c_c, &hA, &hB, &prog, &cons, &out_v, &flag_c };
    hipLaunchCooperativeKernel((void*)k_main, dim3(256), dim3(512), ka, 0, stream);
}

// Round 5
// 818.484 us; speedup vs baseline: 3.2079x; 1.7916x over previous
//
#include <hip/hip_runtime.h>
#include <hip/hip_bf16.h>

typedef __bf16 bf16;
typedef unsigned long long u64;
typedef __bf16 bf16x8 __attribute__((ext_vector_type(8)));
typedef __bf16 bf16x4 __attribute__((ext_vector_type(4)));
typedef float f32x4 __attribute__((ext_vector_type(4)));

#define NB 4
#define T 8192
#define C 128
#define NBLK 40
#define XS 136   // LDS row stride (bf16): 128 ch + 8 pad

#define MFMA(a, b, c) __builtin_amdgcn_mfma_f32_16x16x32_bf16(a, b, c, 0, 0, 0)

__device__ __forceinline__ float bf2f(bf16 x){ return (float)x; }
__device__ __forceinline__ bf16 f2bf(float x){ return (bf16)x; }

__device__ __forceinline__ float ld(const void* p, int i, int isbf){
    return isbf ? bf2f(((const bf16*)p)[i]) : ((const float*)p)[i];
}

// Cross-XCD-coherent 8B h accesses: relaxed agent atomics lower to sc0/sc1
// loads/stores (write-through to IF, bypass stale L1/L2) -> no fences needed.
__device__ __forceinline__ void st8(bf16* p, bf16x4 v){
    __hip_atomic_store((u64*)p, __builtin_bit_cast(u64, v),
                       __ATOMIC_RELAXED, __HIP_MEMORY_SCOPE_AGENT);
}
__device__ __forceinline__ bf16x4 ld8(const bf16* p){
    u64 v = __hip_atomic_load((const u64*)p, __ATOMIC_RELAXED, __HIP_MEMORY_SCOPE_AGENT);
    return __builtin_bit_cast(bf16x4, v);
}

// Detect input dtype from x's raw bits (bf16 -> low u16s have sane exponents).
__global__ __launch_bounds__(64) void k_detect(const unsigned short* __restrict__ u,
                                               int* __restrict__ flag){
    unsigned short v = u[threadIdx.x * 2];
    int e = (v >> 7) & 255;
    bool sane = (e >= 100 && e <= 140) || ((v & 0x7FFF) == 0);
    unsigned long long m = __ballot(sane);
    if (threadIdx.x == 0) *flag = (__popcll(m) >= 48) ? 1 : 0;
}

// Canonicalize inputs: weff [40][256][256] bf16 (K = [tap t-d ch0..127 | tap t ch0..127]),
// pwc [40][128][128] bf16, w1c/w2c bf16, xc f32, cbf/pbf f32,
// misc f32: [0,384) pre_w, [384,512) pre_b, [512,640) lin1_b, [640,768) lin2_b
__global__ __launch_bounds__(256) void k_prep(
    const void* __restrict__ conv_w, const void* __restrict__ post_w,
    const void* __restrict__ lin1_w, const void* __restrict__ lin2_w,
    const void* __restrict__ x,      const void* __restrict__ conv_b,
    const void* __restrict__ post_b, const void* __restrict__ pre_w,
    const void* __restrict__ pre_b,  const void* __restrict__ lin1_b,
    const void* __restrict__ lin2_b,
    bf16* __restrict__ weff, bf16* __restrict__ pwc,
    bf16* __restrict__ w1c,  bf16* __restrict__ w2c,
    float* __restrict__ xc,  float* __restrict__ cbf,
    float* __restrict__ pbf, float* __restrict__ misc,
    const int* __restrict__ flag){
    int f   = *flag;
    int blk = blockIdx.x, tid = threadIdx.x;
    if (blk < 10240){
        int e = blk * 256 + tid;
        int b_ = e >> 16, o = (e >> 8) & 255, c = (e >> 1) & 127, k = e & 1;
        weff[(b_ << 16) + o * 256 + k * 128 + c] = f2bf(ld(conv_w, e, f));
    } else if (blk < 12800){
        int e = (blk - 10240) * 256 + tid;
        pwc[e] = f2bf(ld(post_w, e, f));
    } else if (blk < 12864){
        int e = (blk - 12800) * 256 + tid;
        w1c[e] = f2bf(ld(lin1_w, e, f));
    } else if (blk < 12928){
        int e = (blk - 12864) * 256 + tid;
        w2c[e] = f2bf(ld(lin2_w, e, f));
    } else if (blk < 13056){
        int e = (blk - 12928) * 256 + tid;
        xc[e] = ld(x, e, f);
    } else if (blk < 13096){
        int e = (blk - 13056) * 256 + tid;
        cbf[e] = ld(conv_b, e, f);
    } else if (blk < 13116){
        int e = (blk - 13096) * 256 + tid;
        pbf[e] = ld(post_b, e, f);
    } else {
        int e = (blk - 13116) * 256 + tid;
        if      (e < 384) misc[e] = ld(pre_w,  e,       f);
        else if (e < 512) misc[e] = ld(pre_b,  e - 384, f);
        else if (e < 640) misc[e] = ld(lin1_b, e - 512, f);
        else if (e < 768) misc[e] = ld(lin2_b, e - 640, f);
    }
}

__device__ __forceinline__ void wait_ge(unsigned* p, unsigned v){
    int guard = 0;
    while (__hip_atomic_load(p, __ATOMIC_RELAXED, __HIP_MEMORY_SCOPE_AGENT) < v){
        __builtin_amdgcn_s_sleep(1);
        if (++guard > (1 << 27)) break;   // failsafe against protocol bugs
    }
}

// Persistent kernel, 256 WGs x 512 threads, 1 WG/CU. WG = (batch b, slab of 128 cols).
// prog[w] = stages published (pre-net=1, layer i done => i+2);
// cons[w] = stages consumed (layer-i halo staging done => i+1).
// Layer i: left dep  prog[w-D] >= i+1, D = max(1, d/128);
//          WAR dep   cons[w+Dprev] >= i  (ping-pong buffer reuse).
// No fences: h data moves via relaxed agent atomics (IF-coherent); the
// vmcnt(0) drain in __syncthreads orders data stores before flag stores.
__global__ __launch_bounds__(512, 2) void k_main(
    const float* __restrict__ xc,  const float* __restrict__ misc,
    const bf16* __restrict__ weff, const float* __restrict__ cbf,
    const bf16* __restrict__ pwc,  const float* __restrict__ pbf,
    const bf16* __restrict__ w1c,  const bf16* __restrict__ w2c,
    bf16* __restrict__ hA, bf16* __restrict__ hB,
    unsigned* __restrict__ prog, unsigned* __restrict__ cons,
    void* __restrict__ outv, const int* __restrict__ flag)
{
    __shared__ __align__(16) bf16 Xo[128 * XS];  // own h^{(i)} tile [col_local][ch] (34,816 B)
    __shared__ __align__(16) bf16 Xh[64 * XS];   // halo tap tile, then S/Z/U (17,408 B)

    int tid  = threadIdx.x;
    int wg   = blockIdx.x;             // 256
    int b    = wg >> 6;
    int slab = wg & 63;
    int t0   = slab * 128;
    int wv = tid >> 6, ln = tid & 63, lo = ln & 15, quad = ln >> 4;
    const size_t hb = (size_t)b * T * C;

    float hreg[32];   // h[c = wv*16+quad*4+r][t = t0+ct*16+lo], idx ct*4+r (ct 0..7)
    float ssum[32];

    // ---- pre-net: hreg + global shadow (atomic) + Xo ----
    {
        const float* xr = xc + b * T;
#pragma unroll
        for (int ct = 0; ct < 8; ct++){
            int t = t0 + ct * 16 + lo;
            float x0 = (t >= 2) ? xr[t - 2] : 0.f;
            float x1 = (t >= 1) ? xr[t - 1] : 0.f;
            float x2 = xr[t];
            bf16x4 hv;
#pragma unroll
            for (int r = 0; r < 4; r++){
                int c = wv * 16 + quad * 4 + r;
                float acc = misc[384 + c] + misc[c*3]*x0 + misc[c*3+1]*x1 + misc[c*3+2]*x2;
                hreg[ct * 4 + r] = acc;
                hv[r] = f2bf(acc);
            }
            st8(hA + hb + (size_t)t * C + wv * 16 + quad * 4, hv);
            *(bf16x4*)(Xo + (ct * 16 + lo) * XS + wv * 16 + quad * 4) = hv;
        }
    }
#pragma unroll
    for (int i = 0; i < 32; i++) ssum[i] = 0.f;
    __syncthreads();                               // drains vmcnt -> h visible
    if (tid == 0)
        __hip_atomic_store(prog + wg, 1u, __ATOMIC_RELAXED, __HIP_MEMORY_SCOPE_AGENT);

    // ---- 40 residual blocks ----
    for (int i = 0; i < NBLK; i++){
        int d = 1 << (i % 10);
        int D = (d >= 128) ? (d >> 7) : 1;
        const bf16* hin  = (i & 1) ? hB : hA;
        bf16*       hout = (i & 1) ? hA : hB;
        const bf16* wb   = weff + ((size_t)i << 16);
        const bf16* pwb  = pwc  + i * 16384;
        const float* cb  = cbf + i * 256;
        const float* pb  = pbf + i * 128;

        for (int H = 0; H < 2; H++){
            f32x4 cacc[2][4] = {};
            // --- tap-t (own data, from Xo): independent of neighbors ---
            if (H == 0){
#pragma unroll
                for (int kk = 0; kk < 4; kk++){
                    int ko = 128 + kk * 32 + quad * 8;
                    bf16x8 a0 = *(const bf16x8*)(wb + (size_t)(wv*16 + lo) * 256 + ko);
                    bf16x8 a1 = *(const bf16x8*)(wb + (size_t)(128 + wv*16 + lo) * 256 + ko);
#pragma unroll
                    for (int ct = 0; ct < 4; ct++){
                        bf16x8 bf_ = *(const bf16x8*)(Xo + (ct*16 + lo) * XS + kk*32 + quad*8);
                        cacc[0][ct] = MFMA(a0, bf_, cacc[0][ct]);
                        cacc[1][ct] = MFMA(a1, bf_, cacc[1][ct]);
                    }
                }
                if (tid == 0){
                    if (slab >= D) wait_ge(prog + (wg - D), (unsigned)(i + 1));
                    if (i >= 1){
                        int dp = 1 << ((i - 1) % 10);
                        int Dp = (dp >= 128) ? (dp >> 7) : 1;
                        if (slab + Dp <= 63) wait_ge(cons + (wg + Dp), (unsigned)i);
                    }
                }
                __syncthreads();
                // stage 64-row halo tile (tap t-d) via coherent atomic loads
                {
                    int tbase = t0 - d;
#pragma unroll
                    for (int j = 0; j < 4; j++){
                        int g = j * 512 + tid;          // 2048 granules of 8B
                        int row = g >> 5, c4 = (g & 31) << 2;
                        int t = tbase + row;
                        bf16x4 v = {};
                        if (t >= 0) v = ld8(hin + hb + (size_t)t * C + c4);
                        *(bf16x4*)(Xh + row * XS + c4) = v;
                    }
                }
                __syncthreads();
            } else {
                // stage first (issue loads), tap-t MFMA overlaps their latency
                {
                    int tbase = t0 + 64 - d;
#pragma unroll
                    for (int j = 0; j < 4; j++){
                        int g = j * 512 + tid;
                        int row = g >> 5, c4 = (g & 31) << 2;
                        int t = tbase + row;
                        bf16x4 v = {};
                        if (t >= 0) v = ld8(hin + hb + (size_t)t * C + c4);
                        *(bf16x4*)(Xh + row * XS + c4) = v;
                    }
                }
#pragma unroll
                for (int kk = 0; kk < 4; kk++){
                    int ko = 128 + kk * 32 + quad * 8;
                    bf16x8 a0 = *(const bf16x8*)(wb + (size_t)(wv*16 + lo) * 256 + ko);
                    bf16x8 a1 = *(const bf16x8*)(wb + (size_t)(128 + wv*16 + lo) * 256 + ko);
#pragma unroll
                    for (int ct = 0; ct < 4; ct++){
                        bf16x8 bf_ = *(const bf16x8*)(Xo + (64 + ct*16 + lo) * XS + kk*32 + quad*8);
                        cacc[0][ct] = MFMA(a0, bf_, cacc[0][ct]);
                        cacc[1][ct] = MFMA(a1, bf_, cacc[1][ct]);
                    }
                }
                __syncthreads();
                if (tid == 0)   // all global reads of h^{(i)} by this WG are done
                    __hip_atomic_store(cons + wg, (unsigned)(i + 1),
                                       __ATOMIC_RELAXED, __HIP_MEMORY_SCOPE_AGENT);
            }

            // --- tap t-d from halo tile ---
#pragma unroll
            for (int kk = 0; kk < 4; kk++){
                int ko = kk * 32 + quad * 8;
                bf16x8 a0 = *(const bf16x8*)(wb + (size_t)(wv*16 + lo) * 256 + ko);
                bf16x8 a1 = *(const bf16x8*)(wb + (size_t)(128 + wv*16 + lo) * 256 + ko);
#pragma unroll
                for (int ct = 0; ct < 4; ct++){
                    bf16x8 bf_ = *(const bf16x8*)(Xh + (ct*16 + lo) * XS + kk*32 + quad*8);
                    cacc[0][ct] = MFMA(a0, bf_, cacc[0][ct]);
                    cacc[1][ct] = MFMA(a1, bf_, cacc[1][ct]);
                }
            }
            __syncthreads();   // Xh tap reads done -> reuse Xh as S

            // --- GLU -> ssum + S(=Xh) ---
#pragma unroll
            for (int ct = 0; ct < 4; ct++){
                int col = ct * 16 + lo;
                bf16x4 sv;
#pragma unroll
                for (int r = 0; r < 4; r++){
                    int j = wv * 16 + quad * 4 + r;
                    float a = cacc[0][ct][r] + cb[j];
                    float g = cacc[1][ct][r] + cb[128 + j];
                    float s = a * (1.f / (1.f + __expf(-g)));
                    ssum[(H * 4 + ct) * 4 + r] += s;
                    sv[r] = f2bf(s);
                }
                *(bf16x4*)(Xh + col * XS + wv * 16 + quad * 4) = sv;
            }
            __syncthreads();

            // --- post GEMM + residual + publish-data ---
            f32x4 pacc[4] = {};
#pragma unroll
            for (int kk = 0; kk < 4; kk++){
                bf16x8 pa = *(const bf16x8*)(pwb + (wv*16 + lo) * 128 + kk*32 + quad*8);
#pragma unroll
                for (int ct = 0; ct < 4; ct++){
                    bf16x8 pbv = *(const bf16x8*)(Xh + (ct*16 + lo) * XS + kk*32 + quad*8);
                    pacc[ct] = MFMA(pa, pbv, pacc[ct]);
                }
            }
#pragma unroll
            for (int ct = 0; ct < 4; ct++){
                int t = t0 + H * 64 + ct * 16 + lo;
                bf16x4 hv;
#pragma unroll
                for (int r = 0; r < 4; r++){
                    int row = wv * 16 + quad * 4 + r;
                    float hn = hreg[(H * 4 + ct) * 4 + r] + pacc[ct][r] + pb[row];
                    hreg[(H * 4 + ct) * 4 + r] = hn;
                    hv[r] = f2bf(hn);
                }
                st8(hout + hb + (size_t)t * C + wv * 16 + quad * 4, hv);
                *(bf16x4*)(Xo + (H * 64 + ct * 16 + lo) * XS + wv * 16 + quad * 4) = hv;
            }
            __syncthreads();   // S reads done; h stores drained (vmcnt 0); Xh free
        }

        if (tid == 0){
            asm volatile("s_waitcnt vmcnt(0)" ::: "memory");
            __hip_atomic_store(prog + wg, (unsigned)(i + 2),
                               __ATOMIC_RELAXED, __HIP_MEMORY_SCOPE_AGENT);
        }
    }

    // ---- final: relu(ssum) -> lin1 -> relu -> lin2 -> out [T][B][C] ----
    const float* b1 = misc + 512;
    const float* b2 = misc + 640;
    int isbf = *flag;
    for (int H = 0; H < 2; H++){
#pragma unroll
        for (int ct = 0; ct < 4; ct++){
            int col = ct * 16 + lo;
            bf16x4 zv;
#pragma unroll
            for (int r = 0; r < 4; r++){
                float z = ssum[(H * 4 + ct) * 4 + r];
                zv[r] = f2bf(z > 0.f ? z : 0.f);
            }
            *(bf16x4*)(Xh + col * XS + wv * 16 + quad * 4) = zv;
        }
        __syncthreads();
        f32x4 a1[4] = {};
#pragma unroll
        for (int kk = 0; kk < 4; kk++){
            bf16x8 pa = *(const bf16x8*)(w1c + (wv*16 + lo) * 128 + kk*32 + quad*8);
#pragma unroll
            for (int ct = 0; ct < 4; ct++){
                bf16x8 pbv = *(const bf16x8*)(Xh + (ct*16 + lo) * XS + kk*32 + quad*8);
                a1[ct] = MFMA(pa, pbv, a1[ct]);
            }
        }
        __syncthreads();
#pragma unroll
        for (int ct = 0; ct < 4; ct++){
            int col = ct * 16 + lo;
            bf16x4 uv;
#pragma unroll
            for (int r = 0; r < 4; r++){
                int row = wv * 16 + quad * 4 + r;
                float u = a1[ct][r] + b1[row];
                uv[r] = f2bf(u > 0.f ? u : 0.f);
            }
            *(bf16x4*)(Xh + col * XS + wv * 16 + quad * 4) = uv;
        }
        __syncthreads();
        f32x4 a2[4] = {};
#pragma unroll
        for (int kk = 0; kk < 4; kk++){
            bf16x8 pa = *(const bf16x8*)(w2c + (wv*16 + lo) * 128 + kk*32 + quad*8);
#pragma unroll
            for (int ct = 0; ct < 4; ct++){
                bf16x8 pbv = *(const bf16x8*)(Xh + (ct*16 + lo) * XS + kk*32 + quad*8);
                a2[ct] = MFMA(pa, pbv, a2[ct]);
            }
        }
#pragma unroll
        for (int ct = 0; ct < 4; ct++){
            int col = t0 + H * 64 + ct * 16 + lo;
#pragma unroll
            for (int r = 0; r < 4; r++){
                int row = wv * 16 + quad * 4 + r;
                float v = a2[ct][r] + b2[row];
                size_t oi = ((size_t)col * NB + b) * C + row;
                if (isbf) ((bf16*)outv)[oi] = f2bf(v);
                else      ((float*)outv)[oi] = v;
            }
        }
        __syncthreads();   // U reads done before next half reuses Xh
    }
}

extern "C" void kernel_launch(void* const* d_in, const int* in_sizes, int n_in,
                              void* d_out, int out_size, void* d_ws, size_t ws_size,
                              hipStream_t stream){
    const void* x      = d_in[0];
    const void* pre_w  = d_in[1];
    const void* pre_b  = d_in[2];
    const void* conv_w = d_in[3];
    const void* conv_b = d_in[4];
    const void* post_w = d_in[5];
    const void* post_b = d_in[6];
    const void* lin1w  = d_in[7];
    const void* lin1b  = d_in[8];
    const void* lin2w  = d_in[9];
    const void* lin2b  = d_in[10];

    char* ws = (char*)d_ws;
    bf16*     hA   = (bf16*)    (ws);                   //  8,388,608 B
    bf16*     hB   = (bf16*)    (ws +  8388608);        //  8,388,608 B
    bf16*     weff = (bf16*)    (ws + 16777216);        //  5,242,880 B
    bf16*     pwc  = (bf16*)    (ws + 22020096);        //  1,310,720 B
    bf16*     w1c  = (bf16*)    (ws + 23330816);        //     32,768 B
    bf16*     w2c  = (bf16*)    (ws + 23363584);        //     32,768 B
    float*    xc   = (float*)   (ws + 23396352);        //    131,072 B
    float*    cbf  = (float*)   (ws + 23527424);        //     40,960 B
    float*    pbf  = (float*)   (ws + 23568384);        //     20,480 B
    float*    misc = (float*)   (ws + 23588864);        //      3,072 B
    int*      flag = (int*)     (ws + 23591936);        //          4 B
    unsigned* prog = (unsigned*)(ws + 23592960);        //      1,024 B
    unsigned* cons = (unsigned*)(ws + 23593984);        //      1,024 B

    hipMemsetAsync(prog, 0, 2048, stream);
    k_detect<<<1, 64, 0, stream>>>((const unsigned short*)x, flag);
    k_prep<<<13119, 256, 0, stream>>>(conv_w, post_w, lin1w, lin2w, x, conv_b,
                                      post_b, pre_w, pre_b, lin1b, lin2b,
                                      weff, pwc, w1c, w2c, xc, cbf, pbf, misc, flag);

    const float* xc_c   = xc;   const float* misc_c = misc;
    const bf16*  weff_c = weff; const float* cbf_c  = cbf;
    const bf16*  pwc_c  = pwc;  const float* pbf_c  = pbf;
    const bf16*  w1c_c  = w1c;  const bf16*  w2c_c  = w2c;
    void* out_v = d_out;        const int* flag_c = flag;
    void* ka[14] = { &xc_c, &misc_c, &weff_c, &cbf_c, &pwc_c, &pbf_c,
                     &w1c_c, &w2c_c, &hA, &hB, &prog, &cons, &out_v, &flag_c };
    hipLaunchCooperativeKernel((void*)k_main, dim3(256), dim3(512), ka, 0, stream);
}

// Round 8
// 740.752 us; speedup vs baseline: 3.5445x; 1.1049x over previous
//
#include <hip/hip_runtime.h>
#include <hip/hip_bf16.h>

typedef __bf16 bf16;
typedef unsigned long long u64;
typedef __bf16 bf16x8 __attribute__((ext_vector_type(8)));
typedef __bf16 bf16x4 __attribute__((ext_vector_type(4)));
typedef float f32x4 __attribute__((ext_vector_type(4)));

#define NB 4
#define T 8192
#define C 128
#define NBLK 40
#define XS 136   // LDS row stride (bf16): 128 ch + 8 pad

#define MFMA(a, b, c) __builtin_amdgcn_mfma_f32_16x16x32_bf16(a, b, c, 0, 0, 0)

__device__ __forceinline__ float bf2f(bf16 x){ return (float)x; }
__device__ __forceinline__ bf16 f2bf(float x){ return (bf16)x; }

__device__ __forceinline__ float ld(const void* p, int i, int isbf){
    return isbf ? bf2f(((const bf16*)p)[i]) : ((const float*)p)[i];
}

// Coherent 8B load (relaxed agent atomic -> sc0/sc1, bypasses stale L1/L2;
// compiler manages the waitcnt before use -> no inline-asm readback hazard).
__device__ __forceinline__ bf16x4 ld8(const bf16* p){
    u64 v = __hip_atomic_load((const u64*)p, __ATOMIC_RELAXED, __HIP_MEMORY_SCOPE_AGENT);
    return __builtin_bit_cast(bf16x4, v);
}
// Coherent 16B store via asm (inputs only -> safe), caller drains vmcnt.
__device__ __forceinline__ void st16c(bf16* p, f32x4 v){
    asm volatile("global_store_dwordx4 %0, %1, off sc0 sc1" :: "v"(p), "v"(v) : "memory");
}

// Detect input dtype from x's raw bits (bf16 -> low u16s have sane exponents).
__global__ __launch_bounds__(64) void k_detect(const unsigned short* __restrict__ u,
                                               int* __restrict__ flag){
    unsigned short v = u[threadIdx.x * 2];
    int e = (v >> 7) & 255;
    bool sane = (e >= 100 && e <= 140) || ((v & 0x7FFF) == 0);
    unsigned long long m = __ballot(sane);
    if (threadIdx.x == 0) *flag = (__popcll(m) >= 48) ? 1 : 0;
}

// Canonicalize inputs (8 elems per thread).
// weff [40][256][256] bf16: weff[blk][o][c]=cw[blk][o][c][0] (t-d), [o][128+c]=cw[..][1] (t)
// conv_w element index = blk*65536 + o*256 + c*2 + k   (row stride 256)
// misc f32: [0,384) pre_w, [384,512) pre_b, [512,640) lin1_b, [640,768) lin2_b
__global__ __launch_bounds__(256) void k_prep(
    const void* __restrict__ conv_w, const void* __restrict__ post_w,
    const void* __restrict__ lin1_w, const void* __restrict__ lin2_w,
    const void* __restrict__ x,      const void* __restrict__ conv_b,
    const void* __restrict__ post_b, const void* __restrict__ pre_w,
    const void* __restrict__ pre_b,  const void* __restrict__ lin1_b,
    const void* __restrict__ lin2_b,
    bf16* __restrict__ weff, bf16* __restrict__ pwc,
    bf16* __restrict__ w1c,  bf16* __restrict__ w2c,
    float* __restrict__ xc,  float* __restrict__ cbf,
    float* __restrict__ pbf, float* __restrict__ misc,
    const int* __restrict__ flag){
    int f = *flag;
    int g = blockIdx.x * 256 + threadIdx.x;
    if (g < 327680){                 // weff: 40*256*256/8 granules
        int blk = g >> 13, r = g & 8191, o = r >> 5, j = r & 31;
        int k = (j >= 16) ? 1 : 0;
        int base = blk * 65536 + o * 256 + (j * 8 - k * 128) * 2 + k;
        bf16x8 v;
#pragma unroll
        for (int m = 0; m < 8; m++) v[m] = f2bf(ld(conv_w, base + m * 2, f));
        *(bf16x8*)(weff + (size_t)g * 8) = v;
    } else if (g < 409600){          // pwc
        int e = (g - 327680) * 8;
        bf16x8 v;
#pragma unroll
        for (int m = 0; m < 8; m++) v[m] = f2bf(ld(post_w, e + m, f));
        *(bf16x8*)(pwc + e) = v;
    } else if (g < 411648){          // w1c
        int e = (g - 409600) * 8;
        bf16x8 v;
#pragma unroll
        for (int m = 0; m < 8; m++) v[m] = f2bf(ld(lin1_w, e + m, f));
        *(bf16x8*)(w1c + e) = v;
    } else if (g < 413696){          // w2c
        int e = (g - 411648) * 8;
        bf16x8 v;
#pragma unroll
        for (int m = 0; m < 8; m++) v[m] = f2bf(ld(lin2_w, e + m, f));
        *(bf16x8*)(w2c + e) = v;
    } else if (g < 417792){          // xc (f32)
        int e = (g - 413696) * 8;
#pragma unroll
        for (int m = 0; m < 8; m++) xc[e + m] = ld(x, e + m, f);
    } else if (g < 419072){          // cbf
        int e = (g - 417792) * 8;
#pragma unroll
        for (int m = 0; m < 8; m++) cbf[e + m] = ld(conv_b, e + m, f);
    } else if (g < 419712){          // pbf
        int e = (g - 419072) * 8;
#pragma unroll
        for (int m = 0; m < 8; m++) pbf[e + m] = ld(post_b, e + m, f);
    } else if (g < 419808){          // misc
        int e = (g - 419712) * 8;
#pragma unroll
        for (int m = 0; m < 8; m++){
            int idx = e + m;
            if      (idx < 384) misc[idx] = ld(pre_w,  idx,       f);
            else if (idx < 512) misc[idx] = ld(pre_b,  idx - 384, f);
            else if (idx < 640) misc[idx] = ld(lin1_b, idx - 512, f);
            else                misc[idx] = ld(lin2_b, idx - 640, f);
        }
    }
}

__device__ __forceinline__ void wait_ge(unsigned* p, unsigned v){
    int guard = 0;
    while (__hip_atomic_load(p, __ATOMIC_RELAXED, __HIP_MEMORY_SCOPE_AGENT) < v){
        __builtin_amdgcn_s_sleep(1);
        if (++guard > (1 << 22)) break;   // failsafe against protocol bugs
    }
}

// Store tail rows [128-nrows, 128) of Xo to dst (global, coherent), then drain.
// One row = 128 bf16 = 256 B = SIXTEEN 16B granules (R7 bug: used 8 -> half
// the channels never stored -> absmax 0.34).
__device__ __forceinline__ void tail_store(const bf16* Xo, bf16* dst, int nrows, int tid){
    int ngr = nrows * 16;                      // 16B granules
    for (int g = tid; g < ngr; g += 512){
        int rr = 128 - nrows + (g >> 4), co = (g & 15) * 8;
        f32x4 v = *(const f32x4*)(Xo + rr * XS + co);
        st16c(dst + (size_t)rr * C + co, v);
    }
    asm volatile("s_waitcnt vmcnt(0)" ::: "memory");
}

// Persistent kernel, 256 WGs x 512 threads, 1 WG/CU. WG = (batch b, slab of 128 cols).
// prog[w] = stages published (pre=1, layer i => i+2); cons[w] = staging reads done.
// Only tail rows min(d_next,128) cross slab boundaries -> only those are stored.
__global__ __launch_bounds__(512, 2) void k_main(
    const float* __restrict__ xc,  const float* __restrict__ misc,
    const bf16* __restrict__ weff, const float* __restrict__ cbf,
    const bf16* __restrict__ pwc,  const float* __restrict__ pbf,
    const bf16* __restrict__ w1c,  const bf16* __restrict__ w2c,
    bf16* __restrict__ hA, bf16* __restrict__ hB,
    unsigned* __restrict__ prog, unsigned* __restrict__ cons,
    void* __restrict__ outv, const int* __restrict__ flag)
{
    __shared__ __align__(16) bf16 Xo[128 * XS];  // own h^{(i)} tile [row][ch] (34,816 B)
    __shared__ __align__(16) bf16 Xh[64 * XS];   // tap tile / S / Z / U (17,408 B)

    int tid  = threadIdx.x;
    int wg   = blockIdx.x;             // 256
    int b    = wg >> 6;
    int slab = wg & 63;
    int t0   = slab * 128;
    int wv = tid >> 6, ln = tid & 63, lo = ln & 15, quad = ln >> 4;
    const size_t hb = (size_t)b * T * C;

    float hreg[32];   // h[c = wv*16+quad*4+r][t = t0+ct*16+lo], idx ct*4+r (ct 0..7)
    float ssum[32];

    // ---- pre-net: hreg + Xo; tail-store 1 row (layer-0 d=1) ----
    {
        const float* xr = xc + b * T;
#pragma unroll
        for (int ct = 0; ct < 8; ct++){
            int t = t0 + ct * 16 + lo;
            float x0 = (t >= 2) ? xr[t - 2] : 0.f;
            float x1 = (t >= 1) ? xr[t - 1] : 0.f;
            float x2 = xr[t];
            bf16x4 hv;
#pragma unroll
            for (int r = 0; r < 4; r++){
                int c = wv * 16 + quad * 4 + r;
                float acc = misc[384 + c] + misc[c*3]*x0 + misc[c*3+1]*x1 + misc[c*3+2]*x2;
                hreg[ct * 4 + r] = acc;
                hv[r] = f2bf(acc);
            }
            *(bf16x4*)(Xo + (ct * 16 + lo) * XS + wv * 16 + quad * 4) = hv;
        }
    }
#pragma unroll
    for (int i = 0; i < 32; i++) ssum[i] = 0.f;
    __syncthreads();
    if (slab < 63) tail_store(Xo, hA + hb + (size_t)t0 * C, 1, tid);
    __syncthreads();
    if (tid == 0)
        __hip_atomic_store(prog + wg, 1u, __ATOMIC_RELAXED, __HIP_MEMORY_SCOPE_AGENT);

    // ---- 40 residual blocks ----
    for (int i = 0; i < NBLK; i++){
        int d  = 1 << (i % 10);
        int D  = (d >= 128) ? (d >> 7) : 1;
        int dn = (i < NBLK - 1) ? (1 << ((i + 1) % 10)) : 0;
        int Dn = (dn >= 128) ? (dn >> 7) : 1;
        int nst = (dn < 128) ? dn : 128;
        bool last = (i == NBLK - 1);
        bool do_store = !last && (slab + Dn <= 63);
        const bf16* hin  = (i & 1) ? hB : hA;
        bf16*       hout = (i & 1) ? hA : hB;
        const bf16* wb   = weff + ((size_t)i << 16);
        const bf16* pwb  = pwc  + i * 16384;
        const float* cb  = cbf + i * 256;
        const float* pb  = pbf + i * 128;

        // ================= H = 0 =================
        {
            f32x4 cacc0[4] = {}, cacc1[4] = {};
            // tap-t MFMA from Xo rows 0..63 (stage i, no deps)
#pragma unroll
            for (int kk = 0; kk < 4; kk++){
                int ko = 128 + kk * 32 + quad * 8;
                bf16x8 a0 = *(const bf16x8*)(wb + (size_t)(wv*16 + lo) * 256 + ko);
                bf16x8 a1 = *(const bf16x8*)(wb + (size_t)(128 + wv*16 + lo) * 256 + ko);
#pragma unroll
                for (int ct = 0; ct < 4; ct++){
                    bf16x8 bf_ = *(const bf16x8*)(Xo + (ct*16 + lo) * XS + kk*32 + quad*8);
                    cacc0[ct] = MFMA(a0, bf_, cacc0[ct]);
                    cacc1[ct] = MFMA(a1, bf_, cacc1[ct]);
                }
            }
            if (tid == 0){
                if (slab >= D) wait_ge(prog + (wg - D), (unsigned)(i + 1));
                if (do_store && i >= 1){
                    int dp = 1 << ((i - 1) % 10);
                    int Dp = (dp >= 128) ? (dp >> 7) : 1;
                    if (slab + Dp <= 63) wait_ge(cons + (wg + Dp), (unsigned)i);
                }
            }
            __syncthreads();                                   // B1
            // stage tap t-d tile: global (coherent 8B) for t<t0, Xo copy for t>=t0
            {
                int tbase = t0 - d;
#pragma unroll
                for (int j = 0; j < 4; j++){
                    int g = j * 512 + tid;          // 2048 granules of 8B
                    int row = g >> 5, c4 = (g & 31) << 2;
                    int t = tbase + row;
                    bf16x4 v = {};
                    if (t >= t0)      v = *(const bf16x4*)(Xo + (t - t0) * XS + c4);
                    else if (t >= 0)  v = ld8(hin + hb + (size_t)t * C + c4);
                    *(bf16x4*)(Xh + row * XS + c4) = v;
                }
            }
            __syncthreads();                                   // B2
            if (d <= 64 && !last && tid == 0)                  // last global-read half
                __hip_atomic_store(cons + wg, (unsigned)(i + 1),
                                   __ATOMIC_RELAXED, __HIP_MEMORY_SCOPE_AGENT);
            // tap t-d MFMA from Xh
#pragma unroll
            for (int kk = 0; kk < 4; kk++){
                int ko = kk * 32 + quad * 8;
                bf16x8 a0 = *(const bf16x8*)(wb + (size_t)(wv*16 + lo) * 256 + ko);
                bf16x8 a1 = *(const bf16x8*)(wb + (size_t)(128 + wv*16 + lo) * 256 + ko);
#pragma unroll
                for (int ct = 0; ct < 4; ct++){
                    bf16x8 bf_ = *(const bf16x8*)(Xh + (ct*16 + lo) * XS + kk*32 + quad*8);
                    cacc0[ct] = MFMA(a0, bf_, cacc0[ct]);
                    cacc1[ct] = MFMA(a1, bf_, cacc1[ct]);
                }
            }
            __syncthreads();                                   // B3: Xh free -> S
            // GLU
#pragma unroll
            for (int ct = 0; ct < 4; ct++){
                int col = ct * 16 + lo;
                bf16x4 sv;
#pragma unroll
                for (int r = 0; r < 4; r++){
                    int j = wv * 16 + quad * 4 + r;
                    float a = cacc0[ct][r] + cb[j];
                    float g = cacc1[ct][r] + cb[128 + j];
                    float s = a * (1.f / (1.f + __expf(-g)));
                    ssum[ct * 4 + r] += s;
                    sv[r] = f2bf(s);
                }
                if (!last) *(bf16x4*)(Xh + col * XS + wv * 16 + quad * 4) = sv;
            }
            __syncthreads();                                   // B4
            if (!last){
                f32x4 pacc[4] = {};
#pragma unroll
                for (int kk = 0; kk < 4; kk++){
                    bf16x8 pa = *(const bf16x8*)(pwb + (wv*16 + lo) * 128 + kk*32 + quad*8);
#pragma unroll
                    for (int ct = 0; ct < 4; ct++){
                        bf16x8 pbv = *(const bf16x8*)(Xh + (ct*16 + lo) * XS + kk*32 + quad*8);
                        pacc[ct] = MFMA(pa, pbv, pacc[ct]);
                    }
                }
#pragma unroll
                for (int ct = 0; ct < 4; ct++)
#pragma unroll
                    for (int r = 0; r < 4; r++)
                        hreg[ct * 4 + r] += pacc[ct][r] + pb[wv * 16 + quad * 4 + r];
            }
            __syncthreads();                                   // B5: S reads done
        }

        // ================= H = 1 =================
        {
            f32x4 cacc0[4] = {}, cacc1[4] = {};
            // stage tap t-d tile for cols 64..127 (global only for t<t0)
            {
                int tbase = t0 + 64 - d;
#pragma unroll
                for (int j = 0; j < 4; j++){
                    int g = j * 512 + tid;
                    int row = g >> 5, c4 = (g & 31) << 2;
                    int t = tbase + row;
                    bf16x4 v = {};
                    if (t >= t0)      v = *(const bf16x4*)(Xo + (t - t0) * XS + c4);
                    else if (t >= 0)  v = ld8(hin + hb + (size_t)t * C + c4);
                    *(bf16x4*)(Xh + row * XS + c4) = v;
                }
            }
            // tap-t MFMA from Xo rows 64..127 (stage i, still intact)
#pragma unroll
            for (int kk = 0; kk < 4; kk++){
                int ko = 128 + kk * 32 + quad * 8;
                bf16x8 a0 = *(const bf16x8*)(wb + (size_t)(wv*16 + lo) * 256 + ko);
                bf16x8 a1 = *(const bf16x8*)(wb + (size_t)(128 + wv*16 + lo) * 256 + ko);
#pragma unroll
                for (int ct = 0; ct < 4; ct++){
                    bf16x8 bf_ = *(const bf16x8*)(Xo + (64 + ct*16 + lo) * XS + kk*32 + quad*8);
                    cacc0[ct] = MFMA(a0, bf_, cacc0[ct]);
                    cacc1[ct] = MFMA(a1, bf_, cacc1[ct]);
                }
            }
            __syncthreads();                                   // B6
            if (d > 64 && !last && tid == 0)
                __hip_atomic_store(cons + wg, (unsigned)(i + 1),
                                   __ATOMIC_RELAXED, __HIP_MEMORY_SCOPE_AGENT);
            // tap t-d MFMA from Xh
#pragma unroll
            for (int kk = 0; kk < 4; kk++){
                int ko = kk * 32 + quad * 8;
                bf16x8 a0 = *(const bf16x8*)(wb + (size_t)(wv*16 + lo) * 256 + ko);
                bf16x8 a1 = *(const bf16x8*)(wb + (size_t)(128 + wv*16 + lo) * 256 + ko);
#pragma unroll
                for (int ct = 0; ct < 4; ct++){
                    bf16x8 bf_ = *(const bf16x8*)(Xh + (ct*16 + lo) * XS + kk*32 + quad*8);
                    cacc0[ct] = MFMA(a0, bf_, cacc0[ct]);
                    cacc1[ct] = MFMA(a1, bf_, cacc1[ct]);
                }
            }
            __syncthreads();                                   // B7
            // GLU
#pragma unroll
            for (int ct = 0; ct < 4; ct++){
                int col = ct * 16 + lo;
                bf16x4 sv;
#pragma unroll
                for (int r = 0; r < 4; r++){
                    int j = wv * 16 + quad * 4 + r;
                    float a = cacc0[ct][r] + cb[j];
                    float g = cacc1[ct][r] + cb[128 + j];
                    float s = a * (1.f / (1.f + __expf(-g)));
                    ssum[(4 + ct) * 4 + r] += s;
                    sv[r] = f2bf(s);
                }
                if (!last) *(bf16x4*)(Xh + col * XS + wv * 16 + quad * 4) = sv;
            }
            __syncthreads();                                   // B8
            if (!last){
                f32x4 pacc[4] = {};
#pragma unroll
                for (int kk = 0; kk < 4; kk++){
                    bf16x8 pa = *(const bf16x8*)(pwb + (wv*16 + lo) * 128 + kk*32 + quad*8);
#pragma unroll
                    for (int ct = 0; ct < 4; ct++){
                        bf16x8 pbv = *(const bf16x8*)(Xh + (ct*16 + lo) * XS + kk*32 + quad*8);
                        pacc[ct] = MFMA(pa, pbv, pacc[ct]);
                    }
                }
#pragma unroll
                for (int ct = 0; ct < 4; ct++)
#pragma unroll
                    for (int r = 0; r < 4; r++)
                        hreg[(4 + ct) * 4 + r] += pacc[ct][r] + pb[wv * 16 + quad * 4 + r];
                // write full stage-(i+1) tile to Xo (both halves)
#pragma unroll
                for (int ct = 0; ct < 8; ct++){
                    bf16x4 hv;
#pragma unroll
                    for (int r = 0; r < 4; r++) hv[r] = f2bf(hreg[ct * 4 + r]);
                    *(bf16x4*)(Xo + (ct * 16 + lo) * XS + wv * 16 + quad * 4) = hv;
                }
            }
            __syncthreads();                                   // B9
        }

        if (do_store) tail_store(Xo, hout + hb + (size_t)t0 * C, nst, tid);
        __syncthreads();                                       // B10
        if (!last && tid == 0)
            __hip_atomic_store(prog + wg, (unsigned)(i + 2),
                               __ATOMIC_RELAXED, __HIP_MEMORY_SCOPE_AGENT);
    }

    // ---- final: relu(ssum) -> lin1 -> relu -> lin2 -> out [T][B][C] ----
    const float* b1 = misc + 512;
    const float* b2 = misc + 640;
    int isbf = *flag;
    for (int H = 0; H < 2; H++){
#pragma unroll
        for (int ct = 0; ct < 4; ct++){
            int col = ct * 16 + lo;
            bf16x4 zv;
#pragma unroll
            for (int r = 0; r < 4; r++){
                float z = ssum[(H * 4 + ct) * 4 + r];
                zv[r] = f2bf(z > 0.f ? z : 0.f);
            }
            *(bf16x4*)(Xh + col * XS + wv * 16 + quad * 4) = zv;
        }
        __syncthreads();
        f32x4 a1[4] = {};
#pragma unroll
        for (int kk = 0; kk < 4; kk++){
            bf16x8 pa = *(const bf16x8*)(w1c + (wv*16 + lo) * 128 + kk*32 + quad*8);
#pragma unroll
            for (int ct = 0; ct < 4; ct++){
                bf16x8 pbv = *(const bf16x8*)(Xh + (ct*16 + lo) * XS + kk*32 + quad*8);
                a1[ct] = MFMA(pa, pbv, a1[ct]);
            }
        }
        __syncthreads();
#pragma unroll
        for (int ct = 0; ct < 4; ct++){
            int col = ct * 16 + lo;
            bf16x4 uv;
#pragma unroll
            for (int r = 0; r < 4; r++){
                int row = wv * 16 + quad * 4 + r;
                float u = a1[ct][r] + b1[row];
                uv[r] = f2bf(u > 0.f ? u : 0.f);
            }
            *(bf16x4*)(Xh + col * XS + wv * 16 + quad * 4) = uv;
        }
        __syncthreads();
        f32x4 a2[4] = {};
#pragma unroll
        for (int kk = 0; kk < 4; kk++){
            bf16x8 pa = *(const bf16x8*)(w2c + (wv*16 + lo) * 128 + kk*32 + quad*8);
#pragma unroll
            for (int ct = 0; ct < 4; ct++){
                bf16x8 pbv = *(const bf16x8*)(Xh + (ct*16 + lo) * XS + kk*32 + quad*8);
                a2[ct] = MFMA(pa, pbv, a2[ct]);
            }
        }
#pragma unroll
        for (int ct = 0; ct < 4; ct++){
            int col = t0 + H * 64 + ct * 16 + lo;
#pragma unroll
            for (int r = 0; r < 4; r++){
                int row = wv * 16 + quad * 4 + r;
                float v = a2[ct][r] + b2[row];
                size_t oi = ((size_t)col * NB + b) * C + row;
                if (isbf) ((bf16*)outv)[oi] = f2bf(v);
                else      ((float*)outv)[oi] = v;
            }
        }
        __syncthreads();
    }
}

extern "C" void kernel_launch(void* const* d_in, const int* in_sizes, int n_in,
                              void* d_out, int out_size, void* d_ws, size_t ws_size,
                              hipStream_t stream){
    const void* x      = d_in[0];
    const void* pre_w  = d_in[1];
    const void* pre_b  = d_in[2];
    const void* conv_w = d_in[3];
    const void* conv_b = d_in[4];
    const void* post_w = d_in[5];
    const void* post_b = d_in[6];
    const void* lin1w  = d_in[7];
    const void* lin1b  = d_in[8];
    const void* lin2w  = d_in[9];
    const void* lin2b  = d_in[10];

    char* ws = (char*)d_ws;
    bf16*     hA   = (bf16*)    (ws);                   //  8,388,608 B
    bf16*     hB   = (bf16*)    (ws +  8388608);        //  8,388,608 B
    bf16*     weff = (bf16*)    (ws + 16777216);        //  5,242,880 B
    bf16*     pwc  = (bf16*)    (ws + 22020096);        //  1,310,720 B
    bf16*     w1c  = (bf16*)    (ws + 23330816);        //     32,768 B
    bf16*     w2c  = (bf16*)    (ws + 23363584);        //     32,768 B
    float*    xc   = (float*)   (ws + 23396352);        //    131,072 B
    float*    cbf  = (float*)   (ws + 23527424);        //     40,960 B
    float*    pbf  = (float*)   (ws + 23568384);        //     20,480 B
    float*    misc = (float*)   (ws + 23588864);        //      3,072 B
    int*      flag = (int*)     (ws + 23591936);        //          4 B
    unsigned* prog = (unsigned*)(ws + 23592960);        //      1,024 B
    unsigned* cons = (unsigned*)(ws + 23593984);        //      1,024 B

    hipMemsetAsync(prog, 0, 2048, stream);
    k_detect<<<1, 64, 0, stream>>>((const unsigned short*)x, flag);
    k_prep<<<1640, 256, 0, stream>>>(conv_w, post_w, lin1w, lin2w, x, conv_b,
                                     post_b, pre_w, pre_b, lin1b, lin2b,
                                     weff, pwc, w1c, w2c, xc, cbf, pbf, misc, flag);

    const float* xc_c   = xc;   const float* misc_c = misc;
    const bf16*  weff_c = weff; const float* cbf_c  = cbf;
    const bf16*  pwc_c  = pwc;  const float* pbf_c  = pbf;
    const bf16*  w1c_c  = w1c;  const bf16*  w2c_c  = w2c;
    void* out_v = d_out;        const int* flag_c = flag;
    void* ka[14] = { &xc_c, &misc_c, &weff_c, &cbf_c, &pwc_c, &pbf_c,
                     &w1c_c, &w2c_c, &hA, &hB, &prog, &cons, &out_v, &flag_c };
    hipLaunchCooperativeKernel((void*)k_main, dim3(256), dim3(512), ka, 0, stream);
}